// Round 7
// baseline (206.241 us; speedup 1.0000x reference)
//
#include <hip/hip_runtime.h>

#define B_ 128
#define T_ 256
#define C_ 512
#define H_ 512
// softmax scale * log2(e):  (1/sqrt(512)) * 1.44269504
#define CSCALE 0.063763824f

typedef _Float16 f16x8 __attribute__((ext_vector_type(8)));
typedef _Float16 f16x4 __attribute__((ext_vector_type(4)));
typedef _Float16 f16x2 __attribute__((ext_vector_type(2)));
typedef float    f32x4 __attribute__((ext_vector_type(4)));
typedef float    f32x16 __attribute__((ext_vector_type(16)));
typedef unsigned int u32;
typedef u32 u32x4 __attribute__((ext_vector_type(4)));

// async global->LDS, 16B per lane; LDS dest must be wave-uniform base (+lane*16)
__device__ __forceinline__ void gld16(const void* gsrc, void* ldst) {
  __builtin_amdgcn_global_load_lds(
      (__attribute__((address_space(1))) void*)gsrc,
      (__attribute__((address_space(3))) void*)ldst, 16, 0, 0);
}

// ---------------------------------------------------------------- convert
__global__ __launch_bounds__(256) void cvt_kernel(
    const float4* __restrict__ x, const float4* __restrict__ wq,
    const float4* __restrict__ wk, const float4* __restrict__ wv,
    f16x4* __restrict__ dst) {
  const int NX = (B_ * T_ * C_) / 4;   // 4,194,304
  const int NW = (H_ * C_) / 4;        // 65,536
  const int total = NX + 3 * NW;
  int gid = blockIdx.x * 256 + threadIdx.x;
  int gsz = gridDim.x * 256;
  for (int i = gid; i < total; i += gsz) {
    float4 f;
    if (i < NX)            f = x[i];
    else if (i < NX + NW)  f = wq[i - NX];
    else if (i < NX + 2*NW) f = wk[i - NX - NW];
    else                   f = wv[i - NX - 2*NW];
    f16x4 u = {(_Float16)f.x, (_Float16)f.y, (_Float16)f.z, (_Float16)f.w};
    dst[i] = u;
  }
}

// ---------------------------------------------------------------- QKV proj
// (FROZEN from R6) 256x256 tile, BK=64, 8 waves, 8-phase counted-vmcnt,
// conflict-free subtile LDS. z=0 -> q; z=1 -> k; z=2 -> v^T [B,H,T].
__global__ __launch_bounds__(512, 2) void proj_kernel(
    const _Float16* __restrict__ xh, const _Float16* __restrict__ wh,
    _Float16* __restrict__ qh, _Float16* __restrict__ kh,
    _Float16* __restrict__ vth) {
  __shared__ _Float16 L[65536];  // 128 KB: [buf][A 16384 f16 | B 16384 f16]

  const int tid  = threadIdx.x;
  const int lane = tid & 63;
  const int wave = tid >> 6;          // 0..7
  const int lr = lane & 15, lk = lane >> 4;
  const int lane8 = lane * 8;         // f16 offset of this lane's 16B slot
  const int wr = wave >> 2, wc = wave & 3;
  const int m0 = blockIdx.x * 256;
  const int n0 = blockIdx.y * 256;
  const int z  = blockIdx.z;
  const _Float16* wz = wh + z * (H_ * C_);

  const int srow = wave * 16 + lr;
  const int scol = lk * 8;
  const _Float16* aS = xh + (size_t)(m0 + srow) * C_ + scol;
  const _Float16* bS = wz + (size_t)(n0 + srow) * C_ + scol;

  f32x4 acc[8][4];
#pragma unroll
  for (int i = 0; i < 8; ++i)
#pragma unroll
    for (int j = 0; j < 4; ++j) acc[i][j] = {0.f, 0.f, 0.f, 0.f};
  f16x8 af[4], bf[4];

  gld16(aS,               &L[(wave) * 512]);
  gld16(aS + 65536,       &L[(8 + wave) * 512]);
  gld16(bS,               &L[16384 + (wave) * 512]);
  gld16(bS + 65536,       &L[16384 + (8 + wave) * 512]);
  gld16(aS + 32,          &L[(16 + wave) * 512]);
  gld16(aS + 65536 + 32,  &L[(16 + 8 + wave) * 512]);
  gld16(bS + 32,          &L[16384 + (16 + wave) * 512]);
  gld16(bS + 65536 + 32,  &L[16384 + (16 + 8 + wave) * 512]);
  asm volatile("s_waitcnt vmcnt(4)" ::: "memory");
  __builtin_amdgcn_s_barrier();

#define PH(BUF, MH, KH, STK, SKK, SBUF, SB, VM) do {                          \
    if ((MH) == 0) {                                                           \
      _Pragma("unroll") for (int ni = 0; ni < 4; ++ni)                         \
        bf[ni] = *(const f16x8*)&L[(BUF) * 32768 + 16384 +                     \
                                   ((KH) * 16 + wc * 4 + ni) * 512 + lane8];   \
    }                                                                          \
    _Pragma("unroll") for (int q = 0; q < 4; ++q)                              \
      af[q] = *(const f16x8*)&L[(BUF) * 32768 +                                \
                                ((KH) * 16 + wr * 8 + (MH) * 4 + q) * 512 +    \
                                lane8];                                        \
    {                                                                          \
      const _Float16* s_ = (SB) ? bS : aS;                                     \
      const int db_ = (SBUF) * 32768 + ((SB) ? 16384 : 0);                     \
      gld16(s_ + (STK) + (SKK) * 32,                                           \
            &L[db_ + ((SKK) * 16 + wave) * 512]);                              \
      gld16(s_ + 65536 + (STK) + (SKK) * 32,                                   \
            &L[db_ + ((SKK) * 16 + 8 + wave) * 512]);                          \
    }                                                                          \
    __builtin_amdgcn_s_barrier();                                              \
    __builtin_amdgcn_s_setprio(1);                                             \
    _Pragma("unroll") for (int q = 0; q < 4; ++q)                              \
      _Pragma("unroll") for (int ni = 0; ni < 4; ++ni)                         \
        acc[(MH) * 4 + q][ni] = __builtin_amdgcn_mfma_f32_16x16x32_f16(        \
            af[q], bf[ni], acc[(MH) * 4 + q][ni], 0, 0, 0);                    \
    __builtin_amdgcn_s_setprio(0);                                             \
    if (VM) asm volatile("s_waitcnt vmcnt(4)" ::: "memory");                   \
    __builtin_amdgcn_s_barrier();                                              \
  } while (0)

#pragma unroll 1
  for (int it = 0; it < 4; ++it) {
    const int k1 = (2 * it + 1) * 64;
    const int k2 = (2 * it + 2 < 8 ? 2 * it + 2 : 7) * 64;
    PH(0, 0, 0, k1, 0, 1, 0, 0);
    PH(0, 1, 0, k1, 0, 1, 1, 1);
    PH(0, 0, 1, k1, 1, 1, 0, 0);
    PH(0, 1, 1, k1, 1, 1, 1, 1);
    PH(1, 0, 0, k2, 0, 0, 0, 0);
    PH(1, 1, 0, k2, 0, 0, 1, 1);
    PH(1, 0, 1, k2, 1, 0, 0, 0);
    PH(1, 1, 1, k2, 1, 0, 1, 1);
  }
#undef PH

  if (z < 2) {
    _Float16* out = (z == 0) ? qh : kh;
#pragma unroll
    for (int mi = 0; mi < 8; ++mi) {
      int mg = m0 + wr * 128 + mi * 16 + lk * 4;
#pragma unroll
      for (int ni = 0; ni < 4; ++ni) {
        int n = n0 + wc * 64 + ni * 16 + lr;
#pragma unroll
        for (int r = 0; r < 4; ++r)
          out[(size_t)(mg + r) * H_ + n] = (_Float16)acc[mi][ni][r];
      }
    }
  } else {
    int bb = m0 >> 8;
#pragma unroll
    for (int mi = 0; mi < 8; ++mi) {
      int ttb = wr * 128 + mi * 16 + lk * 4;
#pragma unroll
      for (int ni = 0; ni < 4; ++ni) {
        int n = n0 + wc * 64 + ni * 16 + lr;
        f16x4 u = {(_Float16)acc[mi][ni][0], (_Float16)acc[mi][ni][1],
                   (_Float16)acc[mi][ni][2], (_Float16)acc[mi][ni][3]};
        *(f16x4*)&vth[(size_t)bb * (H_ * T_) + (size_t)n * T_ + ttb] = u;
      }
    }
  }
}

// ---------------------------------------------------------------- attention
// Software-pipelined swapped-QK^T: the loop body for tile t overlaps
// {softmax(t), pack(t), PV(t)} with {kf(t+1) loads (issued right after the
// Ex read), QK^T(t+1), Ex-write(t+1)} -- QK^T crosses the back-edge so the
// K-load latency and the QK MFMA chain are off tile t's critical path.
// One barrier per tile; Ex double-buffered (write buf^1 while buf is read).
// Own partial is summed from LDS too (frees the register carry).
// setprio(1) around both MFMA clusters (T5). launch_bounds(256,3): 3
// blocks/CU co-resident (VGPR cap 170) for cross-block latency hiding.
__global__ __launch_bounds__(256, 3) void attn_kernel(
    const _Float16* __restrict__ qh, const _Float16* __restrict__ kh,
    const _Float16* __restrict__ vth, float* __restrict__ dout) {
  __shared__ f32x4 Ex[2][4][4][64];  // [buf][wave][chunk][lane] = 32 KB

  const int tid  = threadIdx.x;
  const int lane = tid & 63;
  const int wq   = tid >> 6;          // 0..3 = H-quarter
  const int lq   = lane & 31;         // this lane's q row (within tile)
  const int hi   = lane >> 5;
  const int flat = blockIdx.x;        // 0..1023
  const int xcd  = flat & 7;
  const int rest = flat >> 3;
  const int qb   = 7 - (rest & 7);    // long-first within each XCD stream
  const int g    = rest >> 3;         // 0..15
  const int b    = xcd + (g << 3);    // batch, pinned to XCD b%8
  const int q0   = qb * 32;
  const int nkv  = qb + 1;            // kv tiles of 32
  const int hbase = wq * 128;
  const int qg   = q0 + lq;           // global q row for this lane

  // Q as B-operand frags: lane holds Q[qg][hbase + ks*16 + hi*8 + j]
  f16x8 qf[8];
  const _Float16* qp = qh + ((size_t)b * T_ + qg) * H_ + hbase + hi * 8;
#pragma unroll
  for (int ks = 0; ks < 8; ++ks) qf[ks] = *(const f16x8*)&qp[ks * 16];

  f32x16 ot[4];  // O^T quarter
#pragma unroll
  for (int i = 0; i < 4; ++i) ot[i] = {};
  float m_ = -1e30f, l_ = 0.f;

  const _Float16* kp = kh  + ((size_t)b * T_ + lq) * H_ + hbase + hi * 8;
  const _Float16* vp = vth + ((size_t)b * H_ + hbase + lq) * T_ + hi * 8;

  // ---- prologue: QK^T(0) partial -> Ex[0]
  f16x8 kf[8];
#pragma unroll
  for (int ks = 0; ks < 8; ++ks) kf[ks] = *(const f16x8*)&kp[ks * 16];
  {
    f32x16 s2 = {};
#pragma unroll
    for (int ks = 0; ks < 8; ++ks)
      s2 = __builtin_amdgcn_mfma_f32_32x32x16_f16(kf[ks], qf[ks], s2, 0, 0, 0);
#pragma unroll
    for (int c = 0; c < 4; ++c) {
      f32x4 w4 = {s2[c*4+0], s2[c*4+1], s2[c*4+2], s2[c*4+3]};
      Ex[0][wq][c][lane] = w4;
    }
  }

  for (int kvt = 0; kvt < nkv; ++kvt) {
    const int kv0 = kvt * 32;
    const int buf = kvt & 1;
    const bool more = (kvt + 1 < nkv);
    __syncthreads();  // Ex[buf] complete; prior reads of Ex[buf^1] done

    // ---- sum all 4 partials (16B/lane contiguous reads, conflict-free)
    f32x16 st;
#pragma unroll
    for (int c = 0; c < 4; ++c) {
      f32x4 r0 = Ex[buf][0][c][lane];
      f32x4 r1 = Ex[buf][1][c][lane];
      f32x4 r2 = Ex[buf][2][c][lane];
      f32x4 r3 = Ex[buf][3][c][lane];
      f32x4 r = (r0 + r1) + (r2 + r3);
      st[c*4+0] = r[0]; st[c*4+1] = r[1]; st[c*4+2] = r[2]; st[c*4+3] = r[3];
    }

    // ---- early-issue next tile's K loads (hide L2 latency under softmax)
    if (more) {
#pragma unroll
      for (int ks = 0; ks < 8; ++ks)
        kf[ks] = *(const f16x8*)&kp[(size_t)(kv0 + 32) * H_ + ks * 16];
    }

    // ---- causal mask + in-register softmax (q = lane-local), in place
    float rm = -1e30f;
    const int kvb = kv0 + 4 * hi;
#pragma unroll
    for (int r = 0; r < 16; ++r) {
      int kvg = kvb + (r & 3) + 8 * (r >> 2);
      float v = (kvg > qg) ? -1e30f : st[r];
      st[r] = v;
      rm = fmaxf(rm, v);
    }
    rm = fmaxf(rm, __shfl_xor(rm, 32, 64));

    // defer-max (T13): rescale only when max grew > 64 raw (~e^4 headroom)
    if (__any((int)(rm > m_ + 64.f))) {
      float mn = fmaxf(m_, rm);
      float al = __builtin_amdgcn_exp2f((m_ - mn) * CSCALE);
      m_ = mn; l_ *= al;
#pragma unroll
      for (int i = 0; i < 4; ++i)
#pragma unroll
        for (int e = 0; e < 16; ++e) ot[i][e] *= al;
    }
    float rs = 0.f;
#pragma unroll
    for (int r = 0; r < 16; ++r) {
      st[r] = __builtin_amdgcn_exp2f((st[r] - m_) * CSCALE);
      rs += st[r];
    }
    rs += __shfl_xor(rs, 32, 64);
    l_ += rs;

    // ---- P -> f16 pack + partner exchange -> PV B-frags (two reg-lean groups)
    f16x8 pb0, pb1;
    {
      f16x2 h0 = {(_Float16)st[0], (_Float16)st[1]};
      f16x2 h1 = {(_Float16)st[2], (_Float16)st[3]};
      f16x2 h2 = {(_Float16)st[4], (_Float16)st[5]};
      f16x2 h3 = {(_Float16)st[6], (_Float16)st[7]};
      u32 w0 = __builtin_bit_cast(u32, h0), w1 = __builtin_bit_cast(u32, h1);
      u32 w2 = __builtin_bit_cast(u32, h2), w3 = __builtin_bit_cast(u32, h3);
      u32 s0 = (u32)__shfl_xor((int)w0, 32, 64);
      u32 s1 = (u32)__shfl_xor((int)w1, 32, 64);
      u32 s2 = (u32)__shfl_xor((int)w2, 32, 64);
      u32 s3 = (u32)__shfl_xor((int)w3, 32, 64);
      u32x4 t0 = { hi ? s2 : w0, hi ? s3 : w1, hi ? w2 : s0, hi ? w3 : s1 };
      pb0 = __builtin_bit_cast(f16x8, t0);
    }
    {
      f16x2 h0 = {(_Float16)st[8],  (_Float16)st[9]};
      f16x2 h1 = {(_Float16)st[10], (_Float16)st[11]};
      f16x2 h2 = {(_Float16)st[12], (_Float16)st[13]};
      f16x2 h3 = {(_Float16)st[14], (_Float16)st[15]};
      u32 w0 = __builtin_bit_cast(u32, h0), w1 = __builtin_bit_cast(u32, h1);
      u32 w2 = __builtin_bit_cast(u32, h2), w3 = __builtin_bit_cast(u32, h3);
      u32 s0 = (u32)__shfl_xor((int)w0, 32, 64);
      u32 s1 = (u32)__shfl_xor((int)w1, 32, 64);
      u32 s2 = (u32)__shfl_xor((int)w2, 32, 64);
      u32 s3 = (u32)__shfl_xor((int)w3, 32, 64);
      u32x4 t1 = { hi ? s2 : w0, hi ? s3 : w1, hi ? w2 : s0, hi ? w3 : s1 };
      pb1 = __builtin_bit_cast(f16x8, t1);
    }

    // ---- PV on H-quarter: O^T[32h x 32q] += V^T[32h x 32kv] * P^T
    __builtin_amdgcn_s_setprio(1);
#pragma unroll
    for (int ht = 0; ht < 4; ++ht) {
      f16x8 va0 = *(const f16x8*)&vp[(size_t)(ht * 32) * T_ + kv0];
      f16x8 va1 = *(const f16x8*)&vp[(size_t)(ht * 32) * T_ + kv0 + 16];
      ot[ht] = __builtin_amdgcn_mfma_f32_32x32x16_f16(va0, pb0, ot[ht], 0, 0, 0);
      ot[ht] = __builtin_amdgcn_mfma_f32_32x32x16_f16(va1, pb1, ot[ht], 0, 0, 0);
    }
    __builtin_amdgcn_s_setprio(0);

    // ---- QK^T(t+1) + Ex-write (crosses the back-edge; off t's critical path)
    if (more) {
      f32x16 s2v = {};
      __builtin_amdgcn_s_setprio(1);
#pragma unroll
      for (int ks = 0; ks < 8; ++ks)
        s2v = __builtin_amdgcn_mfma_f32_32x32x16_f16(kf[ks], qf[ks], s2v, 0, 0, 0);
      __builtin_amdgcn_s_setprio(0);
#pragma unroll
      for (int c = 0; c < 4; ++c) {
        f32x4 w4 = {s2v[c*4+0], s2v[c*4+1], s2v[c*4+2], s2v[c*4+3]};
        Ex[buf ^ 1][wq][c][lane] = w4;
      }
    }
  }

  // ---- normalize + store fp32 (lane's q row, wave's 128 H-cols)
  float li = 1.0f / l_;
  float* op = dout + ((size_t)b * T_ + qg) * H_ + hbase + 4 * hi;
#pragma unroll
  for (int ht = 0; ht < 4; ++ht)
#pragma unroll
    for (int rq = 0; rq < 4; ++rq) {
      f32x4 v4 = {ot[ht][rq*4+0] * li, ot[ht][rq*4+1] * li,
                  ot[ht][rq*4+2] * li, ot[ht][rq*4+3] * li};
      *(f32x4*)&op[ht * 32 + rq * 8] = v4;
    }
}

// ---------------------------------------------------------------- launch
extern "C" void kernel_launch(void* const* d_in, const int* in_sizes, int n_in,
                              void* d_out, int out_size, void* d_ws, size_t ws_size,
                              hipStream_t stream) {
  const size_t NXE = (size_t)B_ * T_ * C_;   // 16,777,216
  const size_t NWE = (size_t)3 * H_ * C_;    // 786,432
  const size_t NQE = (size_t)B_ * T_ * H_;   // 16,777,216
  const size_t need = (NXE + NWE + 3 * NQE) * sizeof(_Float16);  // 135,790,592 B
  if (ws_size < need) return;  // loud failure (absmax = max|ref|) -> ws too small

  const float* x  = (const float*)d_in[0];
  const float* wq = (const float*)d_in[1];
  const float* wk = (const float*)d_in[2];
  const float* wv = (const float*)d_in[3];

  _Float16* xh  = (_Float16*)d_ws;
  _Float16* wh  = xh + NXE;
  _Float16* qh  = wh + NWE;
  _Float16* kh  = qh + NQE;
  _Float16* vth = kh + NQE;

  cvt_kernel<<<2048, 256, 0, stream>>>((const float4*)x, (const float4*)wq,
                                       (const float4*)wk, (const float4*)wv,
                                       (f16x4*)xh);
  proj_kernel<<<dim3(128, 2, 3), 512, 0, stream>>>(xh, wh, qh, kh, vth);
  attn_kernel<<<1024, 256, 0, stream>>>(qh, kh, vth, (float*)d_out);
}

// Round 8
// 201.985 us; speedup vs baseline: 1.0211x; 1.0211x over previous
//
#include <hip/hip_runtime.h>

#define B_ 128
#define T_ 256
#define C_ 512
#define H_ 512
// softmax scale * log2(e):  (1/sqrt(512)) * 1.44269504
#define CSCALE 0.063763824f

typedef _Float16 f16x8 __attribute__((ext_vector_type(8)));
typedef _Float16 f16x4 __attribute__((ext_vector_type(4)));
typedef _Float16 f16x2 __attribute__((ext_vector_type(2)));
typedef float    f32x4 __attribute__((ext_vector_type(4)));
typedef float    f32x16 __attribute__((ext_vector_type(16)));
typedef unsigned int u32;
typedef u32 u32x4 __attribute__((ext_vector_type(4)));

// async global->LDS, 16B per lane; LDS dest must be wave-uniform base (+lane*16)
__device__ __forceinline__ void gld16(const void* gsrc, void* ldst) {
  __builtin_amdgcn_global_load_lds(
      (__attribute__((address_space(1))) void*)gsrc,
      (__attribute__((address_space(3))) void*)ldst, 16, 0, 0);
}

// ---------------------------------------------------------------- convert
__global__ __launch_bounds__(256) void cvt_kernel(
    const float4* __restrict__ x, const float4* __restrict__ wq,
    const float4* __restrict__ wk, const float4* __restrict__ wv,
    f16x4* __restrict__ dst) {
  const int NX = (B_ * T_ * C_) / 4;   // 4,194,304
  const int NW = (H_ * C_) / 4;        // 65,536
  const int total = NX + 3 * NW;
  int gid = blockIdx.x * 256 + threadIdx.x;
  int gsz = gridDim.x * 256;
  for (int i = gid; i < total; i += gsz) {
    float4 f;
    if (i < NX)            f = x[i];
    else if (i < NX + NW)  f = wq[i - NX];
    else if (i < NX + 2*NW) f = wk[i - NX - NW];
    else                   f = wv[i - NX - 2*NW];
    f16x4 u = {(_Float16)f.x, (_Float16)f.y, (_Float16)f.z, (_Float16)f.w};
    dst[i] = u;
  }
}

// ---------------------------------------------------------------- QKV proj
// 128x128 tile, BK=32, 4 waves, 3-buffer LDS ring (48 KB -> 3 blocks/CU),
// stage(t+2) issued while computing t, counted vmcnt(4) (never 0 in-loop),
// ONE barrier per K-step. Conflict-free LDS: group g = 16 rows x 32 cols
// (512 f16); slot-in-group = reader lane; gld16 sources pre-permuted to
// match (G21 both-sides). z=0 -> q [B*T,H]; z=1 -> k; z=2 -> v^T [B,H,T].
__global__ __launch_bounds__(256, 2) void proj_kernel(
    const _Float16* __restrict__ xh, const _Float16* __restrict__ wh,
    _Float16* __restrict__ qh, _Float16* __restrict__ kh,
    _Float16* __restrict__ vth) {
  __shared__ _Float16 L[3][2][4096];  // [ring][A|B][128 rows x 32 cols] 48 KB

  const int tid  = threadIdx.x;
  const int lane = tid & 63;
  const int wave = tid >> 6;          // 0..3
  const int lr = lane & 15, lk = lane >> 4;
  const int lane8 = lane * 8;
  const int m0 = blockIdx.x * 128;
  const int n0 = blockIdx.y * 128;
  const int z  = blockIdx.z;
  const _Float16* wz = wh + z * (H_ * C_);

  const int wm = (wave >> 1) * 64;    // wave's 64-row M half
  const int wn = (wave & 1) * 64;     // wave's 64-row N half
  const int ga = (wave >> 1) * 4;     // A group base for reads
  const int gb = (wave & 1) * 4;      // B group base for reads

  // stage source: group g = i*4 + wave holds rows g*16..g*16+15;
  // lane l -> row g*16 + (l&15), col (l>>4)*8
  const _Float16* aS = xh + (size_t)(m0 + wave * 16 + lr) * C_ + lk * 8;
  const _Float16* bS = wz + (size_t)(n0 + wave * 16 + lr) * C_ + lk * 8;

  f32x4 acc[4][4];
#pragma unroll
  for (int i = 0; i < 4; ++i)
#pragma unroll
    for (int j = 0; j < 4; ++j) acc[i][j] = {0.f, 0.f, 0.f, 0.f};

#define STAGE(RB, K0) do {                                                    \
    gld16((const void*)(aS + (K0)),            (void*)&L[RB][0][wave * 512]); \
    gld16((const void*)(aS + 64 * C_ + (K0)),  (void*)&L[RB][0][(4 + wave) * 512]); \
    gld16((const void*)(bS + (K0)),            (void*)&L[RB][1][wave * 512]); \
    gld16((const void*)(bS + 64 * C_ + (K0)),  (void*)&L[RB][1][(4 + wave) * 512]); \
  } while (0)

  // prologue: tiles 0,1 in flight; wait tile0 (oldest 4), keep tile1 flying
  STAGE(0, 0);
  STAGE(1, 32);
  asm volatile("s_waitcnt vmcnt(4)" ::: "memory");
  __builtin_amdgcn_s_barrier();

#pragma unroll 1
  for (int t = 0; t < 16; ++t) {
    const int rb = t % 3;

    f16x8 af[4], bf[4];
#pragma unroll
    for (int mi = 0; mi < 4; ++mi)
      af[mi] = *(const f16x8*)&L[rb][0][(ga + mi) * 512 + lane8];
#pragma unroll
    for (int ni = 0; ni < 4; ++ni)
      bf[ni] = *(const f16x8*)&L[rb][1][(gb + ni) * 512 + lane8];

    if (t + 2 < 16) STAGE((t + 2) % 3, (t + 2) * 32);

    __builtin_amdgcn_s_setprio(1);
#pragma unroll
    for (int mi = 0; mi < 4; ++mi)
#pragma unroll
      for (int ni = 0; ni < 4; ++ni)
        acc[mi][ni] = __builtin_amdgcn_mfma_f32_16x16x32_f16(
            af[mi], bf[ni], acc[mi][ni], 0, 0, 0);
    __builtin_amdgcn_s_setprio(0);

    // next tile (t+1) must have landed before anyone reads it after barrier
    if (t + 2 < 16)      asm volatile("s_waitcnt vmcnt(4)" ::: "memory");
    else if (t == 14)    asm volatile("s_waitcnt vmcnt(0)" ::: "memory");
    __builtin_amdgcn_s_barrier();
  }
#undef STAGE

  // epilogue. D layout: col = lane&15, row = (lane>>4)*4 + r  [m89/m91]
  if (z < 2) {
    _Float16* out = (z == 0) ? qh : kh;
#pragma unroll
    for (int mi = 0; mi < 4; ++mi) {
      int mg = m0 + wm + mi * 16 + lk * 4;
#pragma unroll
      for (int ni = 0; ni < 4; ++ni) {
        int n = n0 + wn + ni * 16 + lr;
#pragma unroll
        for (int r = 0; r < 4; ++r)
          out[(size_t)(mg + r) * H_ + n] = (_Float16)acc[mi][ni][r];
      }
    }
  } else {
    // v^T[b][h][t]; r = consecutive t -> 8B packed store
#pragma unroll
    for (int mi = 0; mi < 4; ++mi) {
      int mbase = m0 + wm + mi * 16 + lk * 4;
      int bb = mbase >> 8, tt = mbase & 255;
#pragma unroll
      for (int ni = 0; ni < 4; ++ni) {
        int n = n0 + wn + ni * 16 + lr;
        f16x4 u = {(_Float16)acc[mi][ni][0], (_Float16)acc[mi][ni][1],
                   (_Float16)acc[mi][ni][2], (_Float16)acc[mi][ni][3]};
        *(f16x4*)&vth[(size_t)bb * (H_ * T_) + (size_t)n * T_ + tt] = u;
      }
    }
  }
}

// ---------------------------------------------------------------- attention
// Software-pipelined swapped-QK^T (R7 structure). R8 fix: launch_bounds
// (256,2) -- the (256,3) cap forced ~86MB of scratch spill traffic (R7
// counters); at 256-VGPR cap the pipeline fits in registers, 2 blocks/CU.
__global__ __launch_bounds__(256, 2) void attn_kernel(
    const _Float16* __restrict__ qh, const _Float16* __restrict__ kh,
    const _Float16* __restrict__ vth, float* __restrict__ dout) {
  __shared__ f32x4 Ex[2][4][4][64];  // [buf][wave][chunk][lane] = 32 KB

  const int tid  = threadIdx.x;
  const int lane = tid & 63;
  const int wq   = tid >> 6;          // 0..3 = H-quarter
  const int lq   = lane & 31;         // this lane's q row (within tile)
  const int hi   = lane >> 5;
  const int flat = blockIdx.x;        // 0..1023
  const int xcd  = flat & 7;
  const int rest = flat >> 3;
  const int qb   = 7 - (rest & 7);    // long-first within each XCD stream
  const int g    = rest >> 3;         // 0..15
  const int b    = xcd + (g << 3);    // batch, pinned to XCD b%8
  const int q0   = qb * 32;
  const int nkv  = qb + 1;            // kv tiles of 32
  const int hbase = wq * 128;
  const int qg   = q0 + lq;           // global q row for this lane

  // Q as B-operand frags: lane holds Q[qg][hbase + ks*16 + hi*8 + j]
  f16x8 qf[8];
  const _Float16* qp = qh + ((size_t)b * T_ + qg) * H_ + hbase + hi * 8;
#pragma unroll
  for (int ks = 0; ks < 8; ++ks) qf[ks] = *(const f16x8*)&qp[ks * 16];

  f32x16 ot[4];  // O^T quarter
#pragma unroll
  for (int i = 0; i < 4; ++i) ot[i] = {};
  float m_ = -1e30f, l_ = 0.f;

  const _Float16* kp = kh  + ((size_t)b * T_ + lq) * H_ + hbase + hi * 8;
  const _Float16* vp = vth + ((size_t)b * H_ + hbase + lq) * T_ + hi * 8;

  // ---- prologue: QK^T(0) partial -> Ex[0]
  f16x8 kf[8];
#pragma unroll
  for (int ks = 0; ks < 8; ++ks) kf[ks] = *(const f16x8*)&kp[ks * 16];
  {
    f32x16 s2 = {};
#pragma unroll
    for (int ks = 0; ks < 8; ++ks)
      s2 = __builtin_amdgcn_mfma_f32_32x32x16_f16(kf[ks], qf[ks], s2, 0, 0, 0);
#pragma unroll
    for (int c = 0; c < 4; ++c) {
      f32x4 w4 = {s2[c*4+0], s2[c*4+1], s2[c*4+2], s2[c*4+3]};
      Ex[0][wq][c][lane] = w4;
    }
  }

  for (int kvt = 0; kvt < nkv; ++kvt) {
    const int kv0 = kvt * 32;
    const int buf = kvt & 1;
    const bool more = (kvt + 1 < nkv);
    __syncthreads();  // Ex[buf] complete; prior reads of Ex[buf^1] done

    // ---- sum all 4 partials (16B/lane contiguous reads, conflict-free)
    f32x16 st;
#pragma unroll
    for (int c = 0; c < 4; ++c) {
      f32x4 r0 = Ex[buf][0][c][lane];
      f32x4 r1 = Ex[buf][1][c][lane];
      f32x4 r2 = Ex[buf][2][c][lane];
      f32x4 r3 = Ex[buf][3][c][lane];
      f32x4 r = (r0 + r1) + (r2 + r3);
      st[c*4+0] = r[0]; st[c*4+1] = r[1]; st[c*4+2] = r[2]; st[c*4+3] = r[3];
    }

    // ---- early-issue next tile's K loads (hide L2 latency under softmax)
    if (more) {
#pragma unroll
      for (int ks = 0; ks < 8; ++ks)
        kf[ks] = *(const f16x8*)&kp[(size_t)(kv0 + 32) * H_ + ks * 16];
    }

    // ---- causal mask + in-register softmax (q = lane-local), in place
    float rm = -1e30f;
    const int kvb = kv0 + 4 * hi;
#pragma unroll
    for (int r = 0; r < 16; ++r) {
      int kvg = kvb + (r & 3) + 8 * (r >> 2);
      float v = (kvg > qg) ? -1e30f : st[r];
      st[r] = v;
      rm = fmaxf(rm, v);
    }
    rm = fmaxf(rm, __shfl_xor(rm, 32, 64));

    // defer-max (T13): rescale only when max grew > 64 raw (~e^4 headroom)
    if (__any((int)(rm > m_ + 64.f))) {
      float mn = fmaxf(m_, rm);
      float al = __builtin_amdgcn_exp2f((m_ - mn) * CSCALE);
      m_ = mn; l_ *= al;
#pragma unroll
      for (int i = 0; i < 4; ++i)
#pragma unroll
        for (int e = 0; e < 16; ++e) ot[i][e] *= al;
    }
    float rs = 0.f;
#pragma unroll
    for (int r = 0; r < 16; ++r) {
      st[r] = __builtin_amdgcn_exp2f((st[r] - m_) * CSCALE);
      rs += st[r];
    }
    rs += __shfl_xor(rs, 32, 64);
    l_ += rs;

    // ---- P -> f16 pack + partner exchange -> PV B-frags (two reg-lean groups)
    f16x8 pb0, pb1;
    {
      f16x2 h0 = {(_Float16)st[0], (_Float16)st[1]};
      f16x2 h1 = {(_Float16)st[2], (_Float16)st[3]};
      f16x2 h2 = {(_Float16)st[4], (_Float16)st[5]};
      f16x2 h3 = {(_Float16)st[6], (_Float16)st[7]};
      u32 w0 = __builtin_bit_cast(u32, h0), w1 = __builtin_bit_cast(u32, h1);
      u32 w2 = __builtin_bit_cast(u32, h2), w3 = __builtin_bit_cast(u32, h3);
      u32 s0 = (u32)__shfl_xor((int)w0, 32, 64);
      u32 s1 = (u32)__shfl_xor((int)w1, 32, 64);
      u32 s2 = (u32)__shfl_xor((int)w2, 32, 64);
      u32 s3 = (u32)__shfl_xor((int)w3, 32, 64);
      u32x4 t0 = { hi ? s2 : w0, hi ? s3 : w1, hi ? w2 : s0, hi ? w3 : s1 };
      pb0 = __builtin_bit_cast(f16x8, t0);
    }
    {
      f16x2 h0 = {(_Float16)st[8],  (_Float16)st[9]};
      f16x2 h1 = {(_Float16)st[10], (_Float16)st[11]};
      f16x2 h2 = {(_Float16)st[12], (_Float16)st[13]};
      f16x2 h3 = {(_Float16)st[14], (_Float16)st[15]};
      u32 w0 = __builtin_bit_cast(u32, h0), w1 = __builtin_bit_cast(u32, h1);
      u32 w2 = __builtin_bit_cast(u32, h2), w3 = __builtin_bit_cast(u32, h3);
      u32 s0 = (u32)__shfl_xor((int)w0, 32, 64);
      u32 s1 = (u32)__shfl_xor((int)w1, 32, 64);
      u32 s2 = (u32)__shfl_xor((int)w2, 32, 64);
      u32 s3 = (u32)__shfl_xor((int)w3, 32, 64);
      u32x4 t1 = { hi ? s2 : w0, hi ? s3 : w1, hi ? w2 : s0, hi ? w3 : s1 };
      pb1 = __builtin_bit_cast(f16x8, t1);
    }

    // ---- PV on H-quarter: O^T[32h x 32q] += V^T[32h x 32kv] * P^T
    __builtin_amdgcn_s_setprio(1);
#pragma unroll
    for (int ht = 0; ht < 4; ++ht) {
      f16x8 va0 = *(const f16x8*)&vp[(size_t)(ht * 32) * T_ + kv0];
      f16x8 va1 = *(const f16x8*)&vp[(size_t)(ht * 32) * T_ + kv0 + 16];
      ot[ht] = __builtin_amdgcn_mfma_f32_32x32x16_f16(va0, pb0, ot[ht], 0, 0, 0);
      ot[ht] = __builtin_amdgcn_mfma_f32_32x32x16_f16(va1, pb1, ot[ht], 0, 0, 0);
    }
    __builtin_amdgcn_s_setprio(0);

    // ---- QK^T(t+1) + Ex-write (crosses the back-edge; off t's critical path)
    if (more) {
      f32x16 s2v = {};
      __builtin_amdgcn_s_setprio(1);
#pragma unroll
      for (int ks = 0; ks < 8; ++ks)
        s2v = __builtin_amdgcn_mfma_f32_32x32x16_f16(kf[ks], qf[ks], s2v, 0, 0, 0);
      __builtin_amdgcn_s_setprio(0);
#pragma unroll
      for (int c = 0; c < 4; ++c) {
        f32x4 w4 = {s2v[c*4+0], s2v[c*4+1], s2v[c*4+2], s2v[c*4+3]};
        Ex[buf ^ 1][wq][c][lane] = w4;
      }
    }
  }

  // ---- normalize + store fp32 (lane's q row, wave's 128 H-cols)
  float li = 1.0f / l_;
  float* op = dout + ((size_t)b * T_ + qg) * H_ + hbase + 4 * hi;
#pragma unroll
  for (int ht = 0; ht < 4; ++ht)
#pragma unroll
    for (int rq = 0; rq < 4; ++rq) {
      f32x4 v4 = {ot[ht][rq*4+0] * li, ot[ht][rq*4+1] * li,
                  ot[ht][rq*4+2] * li, ot[ht][rq*4+3] * li};
      *(f32x4*)&op[ht * 32 + rq * 8] = v4;
    }
}

// ---------------------------------------------------------------- launch
extern "C" void kernel_launch(void* const* d_in, const int* in_sizes, int n_in,
                              void* d_out, int out_size, void* d_ws, size_t ws_size,
                              hipStream_t stream) {
  const size_t NXE = (size_t)B_ * T_ * C_;   // 16,777,216
  const size_t NWE = (size_t)3 * H_ * C_;    // 786,432
  const size_t NQE = (size_t)B_ * T_ * H_;   // 16,777,216
  const size_t need = (NXE + NWE + 3 * NQE) * sizeof(_Float16);  // 135,790,592 B
  if (ws_size < need) return;  // loud failure (absmax = max|ref|) -> ws too small

  const float* x  = (const float*)d_in[0];
  const float* wq = (const float*)d_in[1];
  const float* wk = (const float*)d_in[2];
  const float* wv = (const float*)d_in[3];

  _Float16* xh  = (_Float16*)d_ws;
  _Float16* wh  = xh + NXE;
  _Float16* qh  = wh + NWE;
  _Float16* kh  = qh + NQE;
  _Float16* vth = kh + NQE;

  cvt_kernel<<<2048, 256, 0, stream>>>((const float4*)x, (const float4*)wq,
                                       (const float4*)wk, (const float4*)wv,
                                       (f16x4*)xh);
  proj_kernel<<<dim3(256, 4, 3), dim3(256), 0, stream>>>(xh, wh, qh, kh, vth);
  attn_kernel<<<1024, 256, 0, stream>>>(qh, kh, vth, (float*)d_out);
}

// Round 9
// 186.284 us; speedup vs baseline: 1.1071x; 1.0843x over previous
//
#include <hip/hip_runtime.h>

#define B_ 128
#define T_ 256
#define C_ 512
#define H_ 512
// softmax scale * log2(e):  (1/sqrt(512)) * 1.44269504
#define CSCALE 0.063763824f

typedef _Float16 f16x8 __attribute__((ext_vector_type(8)));
typedef _Float16 f16x4 __attribute__((ext_vector_type(4)));
typedef _Float16 f16x2 __attribute__((ext_vector_type(2)));
typedef float    f32x4 __attribute__((ext_vector_type(4)));
typedef float    f32x16 __attribute__((ext_vector_type(16)));
typedef unsigned int u32;
typedef u32 u32x4 __attribute__((ext_vector_type(4)));

// async global->LDS, 16B per lane; LDS dest must be wave-uniform base (+lane*16)
__device__ __forceinline__ void gld16(const void* gsrc, void* ldst) {
  __builtin_amdgcn_global_load_lds(
      (__attribute__((address_space(1))) void*)gsrc,
      (__attribute__((address_space(3))) void*)ldst, 16, 0, 0);
}

// ---------------------------------------------------------------- convert
__global__ __launch_bounds__(256) void cvt_kernel(
    const float4* __restrict__ x, const float4* __restrict__ wq,
    const float4* __restrict__ wk, const float4* __restrict__ wv,
    f16x4* __restrict__ dst) {
  const int NX = (B_ * T_ * C_) / 4;   // 4,194,304
  const int NW = (H_ * C_) / 4;        // 65,536
  const int total = NX + 3 * NW;
  int gid = blockIdx.x * 256 + threadIdx.x;
  int gsz = gridDim.x * 256;
  for (int i = gid; i < total; i += gsz) {
    float4 f;
    if (i < NX)            f = x[i];
    else if (i < NX + NW)  f = wq[i - NX];
    else if (i < NX + 2*NW) f = wk[i - NX - NW];
    else                   f = wv[i - NX - 2*NW];
    f16x4 u = {(_Float16)f.x, (_Float16)f.y, (_Float16)f.z, (_Float16)f.w};
    dst[i] = u;
  }
}

// ---------------------------------------------------------------- QKV proj
// Z-MERGED: one block computes q, k AND v for its (128M x 64N) tile -- the
// A-tile (x) is staged ONCE per K-step and multiplied against all three
// weight panels. 24 MFMA per wave per barrier-drain (vs 16 at 2x the
// staging) -> barrier stall amortized 3x. Structure = R5's proven 2-barrier
// loop (8-phase and ring variants measured equal/worse at K=512).
// LDS 20 KB single-buffer; conflict-free group layout (group = 16r x 32c,
// slot = reader lane; gld16 sources pre-permuted, G21 both-sides).
// 4 waves (2M x 2N): wave owns 64M x 32N per z. acc[3][4][2] ~= 96 VGPR.
__global__ __launch_bounds__(256, 3) void proj_kernel(
    const _Float16* __restrict__ xh, const _Float16* __restrict__ wh,
    _Float16* __restrict__ qh, _Float16* __restrict__ kh,
    _Float16* __restrict__ vth) {
  __shared__ _Float16 As[8][512];     // 8 KB: A groups (rows g*16..g*16+15)
  __shared__ _Float16 Bs[3][4][512];  // 12 KB: per-z B groups

  const int tid  = threadIdx.x;
  const int lane = tid & 63;
  const int wave = tid >> 6;          // 0..3
  const int lr = lane & 15, lk = lane >> 4;
  const int lane8 = lane * 8;
  const int m0 = blockIdx.x * 128;
  const int n0 = blockIdx.y * 64;

  const int wm = (wave >> 1) * 64;    // wave's M half
  const int wn = (wave & 1) * 32;     // wave's N half (32 of 64)
  const int ga = (wave >> 1) * 4;     // A read-group base
  const int gb = (wave & 1) * 2;      // B read-group base

  // stage sources: group g holds rows g*16+0..15; lane l -> row +(l&15),
  // col (l>>4)*8  (matches gld16's linear lane*16B dest)
  const _Float16* aS  = xh + (size_t)(m0 + wave * 16 + lr) * C_ + lk * 8;
  const _Float16* bS0 = wh + (size_t)(n0 + wave * 16 + lr) * C_ + lk * 8;
  const _Float16* bS1 = bS0 + (size_t)H_ * C_;
  const _Float16* bS2 = bS1 + (size_t)H_ * C_;

  f32x4 acc[3][4][2];
#pragma unroll
  for (int z = 0; z < 3; ++z)
#pragma unroll
    for (int i = 0; i < 4; ++i)
#pragma unroll
      for (int j = 0; j < 2; ++j) acc[z][i][j] = {0.f, 0.f, 0.f, 0.f};

#pragma unroll 1
  for (int k0 = 0; k0 < C_; k0 += 32) {
    __syncthreads();  // previous compute done reading LDS
    gld16((const void*)(aS + k0),           (void*)&As[wave][0]);
    gld16((const void*)(aS + 64 * C_ + k0), (void*)&As[4 + wave][0]);
    gld16((const void*)(bS0 + k0),          (void*)&Bs[0][wave][0]);
    gld16((const void*)(bS1 + k0),          (void*)&Bs[1][wave][0]);
    gld16((const void*)(bS2 + k0),          (void*)&Bs[2][wave][0]);
    __syncthreads();  // staging drained (vmcnt(0) at barrier)

    f16x8 af[4];
#pragma unroll
    for (int mi = 0; mi < 4; ++mi)
      af[mi] = *(const f16x8*)&As[ga + mi][lane8];

#pragma unroll
    for (int z = 0; z < 3; ++z) {
      f16x8 bf0 = *(const f16x8*)&Bs[z][gb][lane8];
      f16x8 bf1 = *(const f16x8*)&Bs[z][gb + 1][lane8];
      __builtin_amdgcn_s_setprio(1);
#pragma unroll
      for (int mi = 0; mi < 4; ++mi) {
        acc[z][mi][0] = __builtin_amdgcn_mfma_f32_16x16x32_f16(
            af[mi], bf0, acc[z][mi][0], 0, 0, 0);
        acc[z][mi][1] = __builtin_amdgcn_mfma_f32_16x16x32_f16(
            af[mi], bf1, acc[z][mi][1], 0, 0, 0);
      }
      __builtin_amdgcn_s_setprio(0);
    }
  }

  // ---- epilogue. D layout: col = lane&15, row = (lane>>4)*4 + r [m89/m91]
#pragma unroll
  for (int z = 0; z < 2; ++z) {
    _Float16* out = (z == 0) ? qh : kh;
#pragma unroll
    for (int mi = 0; mi < 4; ++mi) {
      int mg = m0 + wm + mi * 16 + lk * 4;
#pragma unroll
      for (int ni = 0; ni < 2; ++ni) {
        int n = n0 + wn + ni * 16 + lr;
#pragma unroll
        for (int r = 0; r < 4; ++r)
          out[(size_t)(mg + r) * H_ + n] = (_Float16)acc[z][mi][ni][r];
      }
    }
  }
  // v^T[b][h][t]; r = consecutive t -> 8B packed store
#pragma unroll
  for (int mi = 0; mi < 4; ++mi) {
    int mbase = m0 + wm + mi * 16 + lk * 4;
    int bb = mbase >> 8, tt = mbase & 255;
#pragma unroll
    for (int ni = 0; ni < 2; ++ni) {
      int n = n0 + wn + ni * 16 + lr;
      f16x4 u = {(_Float16)acc[2][mi][ni][0], (_Float16)acc[2][mi][ni][1],
                 (_Float16)acc[2][mi][ni][2], (_Float16)acc[2][mi][ni][3]};
      *(f16x4*)&vth[(size_t)bb * (H_ * T_) + (size_t)n * T_ + tt] = u;
    }
  }
}

// ---------------------------------------------------------------- attention
// (FROZEN from R8 -- measured ~61 us, no spill at (256,2).)
// Software-pipelined swapped-QK^T; one barrier/tile; Ex double-buffered.
__global__ __launch_bounds__(256, 2) void attn_kernel(
    const _Float16* __restrict__ qh, const _Float16* __restrict__ kh,
    const _Float16* __restrict__ vth, float* __restrict__ dout) {
  __shared__ f32x4 Ex[2][4][4][64];  // [buf][wave][chunk][lane] = 32 KB

  const int tid  = threadIdx.x;
  const int lane = tid & 63;
  const int wq   = tid >> 6;          // 0..3 = H-quarter
  const int lq   = lane & 31;         // this lane's q row (within tile)
  const int hi   = lane >> 5;
  const int flat = blockIdx.x;        // 0..1023
  const int xcd  = flat & 7;
  const int rest = flat >> 3;
  const int qb   = 7 - (rest & 7);    // long-first within each XCD stream
  const int g    = rest >> 3;         // 0..15
  const int b    = xcd + (g << 3);    // batch, pinned to XCD b%8
  const int q0   = qb * 32;
  const int nkv  = qb + 1;            // kv tiles of 32
  const int hbase = wq * 128;
  const int qg   = q0 + lq;           // global q row for this lane

  // Q as B-operand frags: lane holds Q[qg][hbase + ks*16 + hi*8 + j]
  f16x8 qf[8];
  const _Float16* qp = qh + ((size_t)b * T_ + qg) * H_ + hbase + hi * 8;
#pragma unroll
  for (int ks = 0; ks < 8; ++ks) qf[ks] = *(const f16x8*)&qp[ks * 16];

  f32x16 ot[4];  // O^T quarter
#pragma unroll
  for (int i = 0; i < 4; ++i) ot[i] = {};
  float m_ = -1e30f, l_ = 0.f;

  const _Float16* kp = kh  + ((size_t)b * T_ + lq) * H_ + hbase + hi * 8;
  const _Float16* vp = vth + ((size_t)b * H_ + hbase + lq) * T_ + hi * 8;

  // ---- prologue: QK^T(0) partial -> Ex[0]
  f16x8 kf[8];
#pragma unroll
  for (int ks = 0; ks < 8; ++ks) kf[ks] = *(const f16x8*)&kp[ks * 16];
  {
    f32x16 s2 = {};
#pragma unroll
    for (int ks = 0; ks < 8; ++ks)
      s2 = __builtin_amdgcn_mfma_f32_32x32x16_f16(kf[ks], qf[ks], s2, 0, 0, 0);
#pragma unroll
    for (int c = 0; c < 4; ++c) {
      f32x4 w4 = {s2[c*4+0], s2[c*4+1], s2[c*4+2], s2[c*4+3]};
      Ex[0][wq][c][lane] = w4;
    }
  }

  for (int kvt = 0; kvt < nkv; ++kvt) {
    const int kv0 = kvt * 32;
    const int buf = kvt & 1;
    const bool more = (kvt + 1 < nkv);
    __syncthreads();  // Ex[buf] complete; prior reads of Ex[buf^1] done

    // ---- sum all 4 partials (16B/lane contiguous reads, conflict-free)
    f32x16 st;
#pragma unroll
    for (int c = 0; c < 4; ++c) {
      f32x4 r0 = Ex[buf][0][c][lane];
      f32x4 r1 = Ex[buf][1][c][lane];
      f32x4 r2 = Ex[buf][2][c][lane];
      f32x4 r3 = Ex[buf][3][c][lane];
      f32x4 r = (r0 + r1) + (r2 + r3);
      st[c*4+0] = r[0]; st[c*4+1] = r[1]; st[c*4+2] = r[2]; st[c*4+3] = r[3];
    }

    // ---- early-issue next tile's K loads (hide L2 latency under softmax)
    if (more) {
#pragma unroll
      for (int ks = 0; ks < 8; ++ks)
        kf[ks] = *(const f16x8*)&kp[(size_t)(kv0 + 32) * H_ + ks * 16];
    }

    // ---- causal mask + in-register softmax (q = lane-local), in place
    float rm = -1e30f;
    const int kvb = kv0 + 4 * hi;
#pragma unroll
    for (int r = 0; r < 16; ++r) {
      int kvg = kvb + (r & 3) + 8 * (r >> 2);
      float v = (kvg > qg) ? -1e30f : st[r];
      st[r] = v;
      rm = fmaxf(rm, v);
    }
    rm = fmaxf(rm, __shfl_xor(rm, 32, 64));

    // defer-max (T13): rescale only when max grew > 64 raw (~e^4 headroom)
    if (__any((int)(rm > m_ + 64.f))) {
      float mn = fmaxf(m_, rm);
      float al = __builtin_amdgcn_exp2f((m_ - mn) * CSCALE);
      m_ = mn; l_ *= al;
#pragma unroll
      for (int i = 0; i < 4; ++i)
#pragma unroll
        for (int e = 0; e < 16; ++e) ot[i][e] *= al;
    }
    float rs = 0.f;
#pragma unroll
    for (int r = 0; r < 16; ++r) {
      st[r] = __builtin_amdgcn_exp2f((st[r] - m_) * CSCALE);
      rs += st[r];
    }
    rs += __shfl_xor(rs, 32, 64);
    l_ += rs;

    // ---- P -> f16 pack + partner exchange -> PV B-frags (two reg-lean groups)
    f16x8 pb0, pb1;
    {
      f16x2 h0 = {(_Float16)st[0], (_Float16)st[1]};
      f16x2 h1 = {(_Float16)st[2], (_Float16)st[3]};
      f16x2 h2 = {(_Float16)st[4], (_Float16)st[5]};
      f16x2 h3 = {(_Float16)st[6], (_Float16)st[7]};
      u32 w0 = __builtin_bit_cast(u32, h0), w1 = __builtin_bit_cast(u32, h1);
      u32 w2 = __builtin_bit_cast(u32, h2), w3 = __builtin_bit_cast(u32, h3);
      u32 s0 = (u32)__shfl_xor((int)w0, 32, 64);
      u32 s1 = (u32)__shfl_xor((int)w1, 32, 64);
      u32 s2 = (u32)__shfl_xor((int)w2, 32, 64);
      u32 s3 = (u32)__shfl_xor((int)w3, 32, 64);
      u32x4 t0 = { hi ? s2 : w0, hi ? s3 : w1, hi ? w2 : s0, hi ? w3 : s1 };
      pb0 = __builtin_bit_cast(f16x8, t0);
    }
    {
      f16x2 h0 = {(_Float16)st[8],  (_Float16)st[9]};
      f16x2 h1 = {(_Float16)st[10], (_Float16)st[11]};
      f16x2 h2 = {(_Float16)st[12], (_Float16)st[13]};
      f16x2 h3 = {(_Float16)st[14], (_Float16)st[15]};
      u32 w0 = __builtin_bit_cast(u32, h0), w1 = __builtin_bit_cast(u32, h1);
      u32 w2 = __builtin_bit_cast(u32, h2), w3 = __builtin_bit_cast(u32, h3);
      u32 s0 = (u32)__shfl_xor((int)w0, 32, 64);
      u32 s1 = (u32)__shfl_xor((int)w1, 32, 64);
      u32 s2 = (u32)__shfl_xor((int)w2, 32, 64);
      u32 s3 = (u32)__shfl_xor((int)w3, 32, 64);
      u32x4 t1 = { hi ? s2 : w0, hi ? s3 : w1, hi ? w2 : s0, hi ? w3 : s1 };
      pb1 = __builtin_bit_cast(f16x8, t1);
    }

    // ---- PV on H-quarter: O^T[32h x 32q] += V^T[32h x 32kv] * P^T
    __builtin_amdgcn_s_setprio(1);
#pragma unroll
    for (int ht = 0; ht < 4; ++ht) {
      f16x8 va0 = *(const f16x8*)&vp[(size_t)(ht * 32) * T_ + kv0];
      f16x8 va1 = *(const f16x8*)&vp[(size_t)(ht * 32) * T_ + kv0 + 16];
      ot[ht] = __builtin_amdgcn_mfma_f32_32x32x16_f16(va0, pb0, ot[ht], 0, 0, 0);
      ot[ht] = __builtin_amdgcn_mfma_f32_32x32x16_f16(va1, pb1, ot[ht], 0, 0, 0);
    }
    __builtin_amdgcn_s_setprio(0);

    // ---- QK^T(t+1) + Ex-write (crosses the back-edge; off t's critical path)
    if (more) {
      f32x16 s2v = {};
      __builtin_amdgcn_s_setprio(1);
#pragma unroll
      for (int ks = 0; ks < 8; ++ks)
        s2v = __builtin_amdgcn_mfma_f32_32x32x16_f16(kf[ks], qf[ks], s2v, 0, 0, 0);
      __builtin_amdgcn_s_setprio(0);
#pragma unroll
      for (int c = 0; c < 4; ++c) {
        f32x4 w4 = {s2v[c*4+0], s2v[c*4+1], s2v[c*4+2], s2v[c*4+3]};
        Ex[buf ^ 1][wq][c][lane] = w4;
      }
    }
  }

  // ---- normalize + store fp32 (lane's q row, wave's 128 H-cols)
  float li = 1.0f / l_;
  float* op = dout + ((size_t)b * T_ + qg) * H_ + hbase + 4 * hi;
#pragma unroll
  for (int ht = 0; ht < 4; ++ht)
#pragma unroll
    for (int rq = 0; rq < 4; ++rq) {
      f32x4 v4 = {ot[ht][rq*4+0] * li, ot[ht][rq*4+1] * li,
                  ot[ht][rq*4+2] * li, ot[ht][rq*4+3] * li};
      *(f32x4*)&op[ht * 32 + rq * 8] = v4;
    }
}

// ---------------------------------------------------------------- launch
extern "C" void kernel_launch(void* const* d_in, const int* in_sizes, int n_in,
                              void* d_out, int out_size, void* d_ws, size_t ws_size,
                              hipStream_t stream) {
  const size_t NXE = (size_t)B_ * T_ * C_;   // 16,777,216
  const size_t NWE = (size_t)3 * H_ * C_;    // 786,432
  const size_t NQE = (size_t)B_ * T_ * H_;   // 16,777,216
  const size_t need = (NXE + NWE + 3 * NQE) * sizeof(_Float16);  // 135,790,592 B
  if (ws_size < need) return;  // loud failure (absmax = max|ref|) -> ws too small

  const float* x  = (const float*)d_in[0];
  const float* wq = (const float*)d_in[1];
  const float* wk = (const float*)d_in[2];
  const float* wv = (const float*)d_in[3];

  _Float16* xh  = (_Float16*)d_ws;
  _Float16* wh  = xh + NXE;
  _Float16* qh  = wh + NWE;
  _Float16* kh  = qh + NQE;
  _Float16* vth = kh + NQE;

  cvt_kernel<<<2048, 256, 0, stream>>>((const float4*)x, (const float4*)wq,
                                       (const float4*)wk, (const float4*)wv,
                                       (f16x4*)xh);
  proj_kernel<<<dim3(256, 8), dim3(256), 0, stream>>>(xh, wh, qh, kh, vth);
  attn_kernel<<<1024, 256, 0, stream>>>(qh, kh, vth, (float*)d_out);
}